// Round 3
// baseline (430.776 us; speedup 1.0000x reference)
//
#include <hip/hip_runtime.h>

#define D 16
#define NW_MAX 256
#define RS_LOG 7
#define RS 128           // nodes per v-range
#define NRANGE_MAX 1024  // supports N <= 131072
#define CHUNK 8192
#define PCAP 4096        // edges per LDS chunk in range_compute

// ---------------- v-range sort build (no contended atomics, no serial scan) --

// K1: global per-range totals, LDS-aggregated.
__global__ __launch_bounds__(256) void histr_kernel(
    const int* __restrict__ v, int* __restrict__ bucketTotal, int E) {
    __shared__ int h[NRANGE_MAX];
    int t = threadIdx.x;
    for (int i = t; i < NRANGE_MAX; i += 256) h[i] = 0;
    __syncthreads();
    int base = blockIdx.x * CHUNK;
    int lim = E - base; if (lim > CHUNK) lim = CHUNK;
    for (int k = t; k < lim; k += 256) atomicAdd(&h[v[base + k] >> RS_LOG], 1);
    __syncthreads();
    for (int i = t; i < NRANGE_MAX; i += 256)
        if (h[i]) atomicAdd(&bucketTotal[i], h[i]);
}

// K2: one 1024-thread block: exclusive scan of range totals -> base & cursor.
__global__ __launch_bounds__(1024) void scanr_kernel(
    const int* __restrict__ bucketTotal, int* __restrict__ bucketBase,
    int* __restrict__ cursor) {
    __shared__ int s[NRANGE_MAX];
    int t = threadIdx.x;
    int mine = bucketTotal[t];
    s[t] = mine;
    __syncthreads();
    for (int d = 1; d < NRANGE_MAX; d <<= 1) {
        int val = s[t];
        int add = (t >= d) ? s[t - d] : 0;
        __syncthreads();
        s[t] = val + add;
        __syncthreads();
    }
    int b = s[t] - mine;  // exclusive
    bucketBase[t] = b;
    cursor[t] = b;
}

// K3: scatter edges into range-contiguous runs. Per-block LDS hist -> one
// global cursor atomic per (block,range) -> LDS-cursor scatter.
// Packs u(17b) | widx(8b)<<17 | vloc(7b)<<25 into one u32.
__global__ __launch_bounds__(256) void scatr_kernel(
    const int* __restrict__ u, const int* __restrict__ v,
    const int* __restrict__ widx, int* __restrict__ cursor,
    unsigned* __restrict__ perm, int E) {
    __shared__ int h[NRANGE_MAX];
    __shared__ int lbase[NRANGE_MAX];
    int t = threadIdx.x;
    for (int i = t; i < NRANGE_MAX; i += 256) h[i] = 0;
    __syncthreads();
    int base = blockIdx.x * CHUNK;
    int lim = E - base; if (lim > CHUNK) lim = CHUNK;
    for (int k = t; k < lim; k += 256) atomicAdd(&h[v[base + k] >> RS_LOG], 1);
    __syncthreads();
    for (int i = t; i < NRANGE_MAX; i += 256) {
        lbase[i] = h[i] ? atomicAdd(&cursor[i], h[i]) : 0;
        h[i] = 0;  // reuse as local cursor
    }
    __syncthreads();
    for (int k = t; k < lim; k += 256) {
        int e = base + k;
        int vv = v[e];
        int r = vv >> RS_LOG;
        int lr = atomicAdd(&h[r], 1);
        perm[lbase[r] + lr] = (unsigned)u[e] | ((unsigned)widx[e] << 17) |
                              ((unsigned)(vv & (RS - 1)) << 25);
    }
}

// K4: per-range fused widx-sort + compute + LDS accumulate + ReLU store.
// Group g (16 lanes) owns widx values [g*16, g*16+16); W register-cached per
// run; per edge: LDS perm broadcast, one coalesced x line, 16 shfl+fma,
// ds_add_f32 into the range's LDS out tile. One coalesced float4 store pass.
__global__ __launch_bounds__(256) void range_compute_kernel(
    const float* __restrict__ x, const float* __restrict__ W,
    const int* __restrict__ bucketBase, const int* __restrict__ bucketEnd,
    const unsigned* __restrict__ perm, float* __restrict__ out, int N) {
    __shared__ float acc[RS * D];      // 8 KB
    __shared__ unsigned eperm[PCAP];   // 16 KB
    __shared__ int h[NW_MAX];          // widx counts
    __shared__ int cb[NW_MAX];         // widx exclusive bases
    __shared__ int hc[NW_MAX];         // widx scatter cursors
    int t = threadIdx.x;
    int r = blockIdx.x;
    int begin = bucketBase[r], end = bucketEnd[r];

    for (int i = t; i < RS * D; i += 256) acc[i] = 0.0f;

    int o = t & 15, g = t >> 4;

    for (int cbase = begin; cbase < end; cbase += PCAP) {
        int cnt = end - cbase; if (cnt > PCAP) cnt = PCAP;

        // Pass A: widx histogram of this chunk.
        h[t] = 0;
        __syncthreads();
        for (int k = t; k < cnt; k += 256)
            atomicAdd(&h[(perm[cbase + k] >> 17) & 255], 1);
        __syncthreads();

        // Pass B: 256-wide Hillis-Steele scan -> cb (exclusive), reset hc.
        int mine = h[t];
        cb[t] = mine;
        __syncthreads();
        for (int d = 1; d < 256; d <<= 1) {
            int val = cb[t];
            int add = (t >= d) ? cb[t - d] : 0;
            __syncthreads();
            cb[t] = val + add;
            __syncthreads();
        }
        cb[t] -= mine;
        hc[t] = 0;
        __syncthreads();

        // Pass C: scatter chunk into widx-ordered LDS array.
        for (int k = t; k < cnt; k += 256) {
            unsigned p = perm[cbase + k];
            int w = (p >> 17) & 255;
            int pos = cb[w] + atomicAdd(&hc[w], 1);
            eperm[pos] = p;
        }
        __syncthreads();

        // Pass D: compute. Control flow is uniform within each 16-lane group.
        for (int wi = 0; wi < 16; ++wi) {
            int w = (g << 4) | wi;
            int c = h[w];
            if (c == 0) continue;
            int s0 = cb[w];
            const float* Wr = W + ((size_t)w << 8) + (o << 4);
            float4 w0 = *(const float4*)(Wr + 0);
            float4 w1 = *(const float4*)(Wr + 4);
            float4 w2 = *(const float4*)(Wr + 8);
            float4 w3 = *(const float4*)(Wr + 12);

            // depth-1 software pipeline on the x gather
            unsigned p = eperm[s0];
            float xv = x[(size_t)(p & 0x1FFFFu) * D + o];
            int vl = (int)(p >> 25);
            for (int i = 1; i <= c; ++i) {
                float xn = 0.0f; int vn = 0;
                if (i < c) {
                    unsigned pn = eperm[s0 + i];
                    xn = x[(size_t)(pn & 0x1FFFFu) * D + o];
                    vn = (int)(pn >> 25);
                }
                float a = 0.0f;
                a += w0.x * __shfl(xv,  0, 16);
                a += w0.y * __shfl(xv,  1, 16);
                a += w0.z * __shfl(xv,  2, 16);
                a += w0.w * __shfl(xv,  3, 16);
                a += w1.x * __shfl(xv,  4, 16);
                a += w1.y * __shfl(xv,  5, 16);
                a += w1.z * __shfl(xv,  6, 16);
                a += w1.w * __shfl(xv,  7, 16);
                a += w2.x * __shfl(xv,  8, 16);
                a += w2.y * __shfl(xv,  9, 16);
                a += w2.z * __shfl(xv, 10, 16);
                a += w2.w * __shfl(xv, 11, 16);
                a += w3.x * __shfl(xv, 12, 16);
                a += w3.y * __shfl(xv, 13, 16);
                a += w3.z * __shfl(xv, 14, 16);
                a += w3.w * __shfl(xv, 15, 16);
                atomicAdd(&acc[(vl << 4) | o], a);
                xv = xn; vl = vn;
            }
        }
        __syncthreads();  // before next chunk reuses h/cb/hc/eperm
    }

    // Pass E: write out with fused ReLU (covers empty nodes with 0).
    __syncthreads();
    int nodeBase = r << RS_LOG;
    int nodes = N - nodeBase; if (nodes > RS) nodes = RS;
    if (nodes <= 0) return;
    int nvec = nodes * (D / 4);
    float4* op = (float4*)(out + (size_t)nodeBase * D);
    for (int i = t; i < nvec; i += 256) {
        float4 val = ((float4*)acc)[i];
        val.x = fmaxf(val.x, 0.0f);
        val.y = fmaxf(val.y, 0.0f);
        val.z = fmaxf(val.z, 0.0f);
        val.w = fmaxf(val.w, 0.0f);
        op[i] = val;
    }
}

// ---------------- Fallback: edge-parallel atomic path ----------------------

__global__ __launch_bounds__(256) void edge_scatter_kernel(
    const float* __restrict__ x, const float* __restrict__ W,
    const int* __restrict__ u, const int* __restrict__ v,
    const int* __restrict__ widx, float* __restrict__ out, int E) {
    int tid = blockIdx.x * 256 + threadIdx.x;
    int e = tid >> 4;
    int o = tid & 15;
    if (e >= E) return;

    int w  = widx[e];
    int uu = u[e];
    int vv = v[e];

    const float* Wr = W + (size_t)w * (D * D) + (size_t)o * D;
    float4 w0 = *(const float4*)(Wr + 0);
    float4 w1 = *(const float4*)(Wr + 4);
    float4 w2 = *(const float4*)(Wr + 8);
    float4 w3 = *(const float4*)(Wr + 12);

    float xv = x[(size_t)uu * D + o];

    float acc = 0.0f;
    acc += w0.x * __shfl(xv,  0, 16);
    acc += w0.y * __shfl(xv,  1, 16);
    acc += w0.z * __shfl(xv,  2, 16);
    acc += w0.w * __shfl(xv,  3, 16);
    acc += w1.x * __shfl(xv,  4, 16);
    acc += w1.y * __shfl(xv,  5, 16);
    acc += w1.z * __shfl(xv,  6, 16);
    acc += w1.w * __shfl(xv,  7, 16);
    acc += w2.x * __shfl(xv,  8, 16);
    acc += w2.y * __shfl(xv,  9, 16);
    acc += w2.z * __shfl(xv, 10, 16);
    acc += w2.w * __shfl(xv, 11, 16);
    acc += w3.x * __shfl(xv, 12, 16);
    acc += w3.y * __shfl(xv, 13, 16);
    acc += w3.z * __shfl(xv, 14, 16);
    acc += w3.w * __shfl(xv, 15, 16);

    atomicAdd(out + (size_t)vv * D + o, acc);
}

__global__ __launch_bounds__(256) void relu_kernel(float* __restrict__ out, int n4) {
    int i = blockIdx.x * 256 + threadIdx.x;
    if (i >= n4) return;
    float4* p = (float4*)out + i;
    float4 val = *p;
    val.x = fmaxf(val.x, 0.0f);
    val.y = fmaxf(val.y, 0.0f);
    val.z = fmaxf(val.z, 0.0f);
    val.w = fmaxf(val.w, 0.0f);
    *p = val;
}

extern "C" void kernel_launch(void* const* d_in, const int* in_sizes, int n_in,
                              void* d_out, int out_size, void* d_ws, size_t ws_size,
                              hipStream_t stream) {
    const float* x    = (const float*)d_in[0];
    const float* W    = (const float*)d_in[1];
    const int*   u    = (const int*)d_in[2];
    const int*   v    = (const int*)d_in[3];
    const int*   widx = (const int*)d_in[4];
    float* out = (float*)d_out;

    int E  = in_sizes[2];           // number of edges
    int NW = in_sizes[1] / (D * D); // number of weight matrices
    int N  = out_size / D;          // number of nodes
    int B  = (E + CHUNK - 1) / CHUNK;
    int NRANGE = (N + RS - 1) >> RS_LOG;

    // Workspace: bucketTotal[1024] | bucketBase[1024] | cursor[1024] | perm[E]
    size_t head = (size_t)NRANGE_MAX * 4 * 3;
    size_t need = head + (size_t)E * 4;

    if (N <= (1 << 17) && NW <= NW_MAX && ws_size >= need) {
        int* bucketTotal = (int*)d_ws;
        int* bucketBase  = (int*)((char*)d_ws + (size_t)NRANGE_MAX * 4);
        int* cursor      = (int*)((char*)d_ws + (size_t)NRANGE_MAX * 8);
        unsigned* perm   = (unsigned*)((char*)d_ws + head);

        hipMemsetAsync(bucketTotal, 0, (size_t)NRANGE_MAX * 4, stream);
        histr_kernel<<<B, 256, 0, stream>>>(v, bucketTotal, E);
        scanr_kernel<<<1, 1024, 0, stream>>>(bucketTotal, bucketBase, cursor);
        scatr_kernel<<<B, 256, 0, stream>>>(u, v, widx, cursor, perm, E);
        // after scatr, cursor[r] == bucketBase[r] + count[r] == end of range r
        range_compute_kernel<<<NRANGE, 256, 0, stream>>>(
            x, W, bucketBase, cursor, perm, out, N);
    } else {
        // Fallback: original atomic-scatter path.
        hipMemsetAsync(d_out, 0, (size_t)out_size * sizeof(float), stream);
        int total_threads = E * 16;
        int blocks = (total_threads + 255) / 256;
        edge_scatter_kernel<<<blocks, 256, 0, stream>>>(x, W, u, v, widx, out, E);
        int n4 = out_size / 4;
        int rblocks = (n4 + 255) / 256;
        relu_kernel<<<rblocks, 256, 0, stream>>>(out, n4);
    }
}

// Round 4
// 199.169 us; speedup vs baseline: 2.1629x; 2.1629x over previous
//
#include <hip/hip_runtime.h>

#define D 16
#define NW_MAX 256
#define CHUNK 2048
#define NSLICE 8

// ---------------- widx-bucket build (parallel scan, no memsets) ------------

// K1: per-block LDS histogram over widx -> counts[w][b] (transposed layout).
// Also zeroes `out` (grid-stride) so no separate memset dispatch is needed.
__global__ __launch_bounds__(256) void hist_kernel(
    const int* __restrict__ widx, int* __restrict__ counts, int BP, int E,
    float4* __restrict__ outz, int n4) {
    __shared__ int h[NW_MAX];
    int t = threadIdx.x;
    // fused out-zeroing
    for (int i = blockIdx.x * 256 + t; i < n4; i += gridDim.x * 256)
        outz[i] = make_float4(0.f, 0.f, 0.f, 0.f);
    h[t] = 0;
    __syncthreads();
    int base = blockIdx.x * CHUNK;
    int lim = E - base; if (lim > CHUNK) lim = CHUNK;
    for (int k = t; k < lim; k += 256)
        atomicAdd(&h[widx[base + k]], 1);
    __syncthreads();
    counts[t * BP + blockIdx.x] = h[t];
}

// K2: parallel per-row exclusive scan. One wave per widx row; coalesced
// 64-wide loads + shfl_up wave scan; counts[w][b] becomes the exclusive
// prefix within row w; rowTotal[w] = row sum.
__global__ __launch_bounds__(256) void rowscan_kernel(
    int* __restrict__ counts, int* __restrict__ rowTotal, int BP, int B) {
    int t = threadIdx.x;
    int w = blockIdx.x * 4 + (t >> 6);   // 64 blocks * 4 waves = 256 rows
    int lane = t & 63;
    int run = 0;
    for (int b0 = 0; b0 < BP; b0 += 64) {
        int b = b0 + lane;
        int val = (b < B) ? counts[w * BP + b] : 0;
        int incl = val;
        #pragma unroll
        for (int d = 1; d < 64; d <<= 1) {
            int tmp = __shfl_up(incl, d, 64);
            if (lane >= d) incl += tmp;
        }
        if (b < B) counts[w * BP + b] = run + incl - val;
        run += __shfl(incl, 63, 64);
    }
    if (lane == 0) rowTotal[w] = run;
}

// K3: one block: exclusive scan of 256 row totals -> bucketBase[0..256].
__global__ __launch_bounds__(256) void basescan_kernel(
    const int* __restrict__ rowTotal, int* __restrict__ bucketBase) {
    __shared__ int s[NW_MAX];
    int t = threadIdx.x;
    int mine = rowTotal[t];
    s[t] = mine;
    __syncthreads();
    for (int d = 1; d < NW_MAX; d <<= 1) {
        int val = s[t];
        int add = (t >= d) ? s[t - d] : 0;
        __syncthreads();
        s[t] = val + add;
        __syncthreads();
    }
    bucketBase[t] = s[t] - mine;
    if (t == NW_MAX - 1) bucketBase[NW_MAX] = s[t];
}

// K4: single-pass scatter into widx-contiguous runs. LDS cursors seeded from
// bucketBase + per-(row,block) exclusive prefix; payload is (u, v) directly.
__global__ __launch_bounds__(256) void scatter_kernel(
    const int* __restrict__ u, const int* __restrict__ v,
    const int* __restrict__ widx, const int* __restrict__ counts,
    const int* __restrict__ bucketBase, uint2* __restrict__ perm,
    int BP, int E) {
    __shared__ int cur[NW_MAX];
    int t = threadIdx.x;
    int b = blockIdx.x;
    cur[t] = bucketBase[t] + counts[t * BP + b];
    __syncthreads();
    int base = b * CHUNK;
    int lim = E - base; if (lim > CHUNK) lim = CHUNK;
    for (int k = t; k < lim; k += 256) {
        int e = base + k;
        int w = widx[e];
        int pos = atomicAdd(&cur[w], 1);
        perm[pos] = make_uint2((unsigned)u[e], (unsigned)v[e]);
    }
}

// K5: compute. One bucket slice per block; W[w] register-cached (lane o holds
// row o). Depth-1 software prefetch of next perm entry + x line. Per edge:
// broadcast perm read, one x line, 16 shfl+fma, one atomicAdd line.
__global__ __launch_bounds__(256) void bucket_mm_kernel(
    const float* __restrict__ x, const float* __restrict__ W,
    const int* __restrict__ bucketBase, const uint2* __restrict__ perm,
    float* __restrict__ out) {
    int w = blockIdx.x >> 3;           // NSLICE = 8
    int s = blockIdx.x & (NSLICE - 1);
    int base = bucketBase[w];
    int cnt  = bucketBase[w + 1] - base;
    int begin = base + (cnt * s) / NSLICE;
    int end   = base + (cnt * (s + 1)) / NSLICE;
    int o = threadIdx.x & 15;
    int g = threadIdx.x >> 4;

    const float* Wr = W + ((size_t)w << 8) + (o << 4);
    float4 w0 = *(const float4*)(Wr + 0);
    float4 w1 = *(const float4*)(Wr + 4);
    float4 w2 = *(const float4*)(Wr + 8);
    float4 w3 = *(const float4*)(Wr + 12);

    int j = begin + g;
    uint2 pe = make_uint2(0u, 0u);
    float xv = 0.0f;
    if (j < end) {
        pe = perm[j];
        xv = x[((size_t)pe.x << 4) + o];
    }
    while (j < end) {
        int jn = j + 16;
        uint2 pn = make_uint2(0u, 0u);
        float xn = 0.0f;
        if (jn < end) {
            pn = perm[jn];
            xn = x[((size_t)pn.x << 4) + o];
        }
        float a = 0.0f;
        a += w0.x * __shfl(xv,  0, 16);
        a += w0.y * __shfl(xv,  1, 16);
        a += w0.z * __shfl(xv,  2, 16);
        a += w0.w * __shfl(xv,  3, 16);
        a += w1.x * __shfl(xv,  4, 16);
        a += w1.y * __shfl(xv,  5, 16);
        a += w1.z * __shfl(xv,  6, 16);
        a += w1.w * __shfl(xv,  7, 16);
        a += w2.x * __shfl(xv,  8, 16);
        a += w2.y * __shfl(xv,  9, 16);
        a += w2.z * __shfl(xv, 10, 16);
        a += w2.w * __shfl(xv, 11, 16);
        a += w3.x * __shfl(xv, 12, 16);
        a += w3.y * __shfl(xv, 13, 16);
        a += w3.z * __shfl(xv, 14, 16);
        a += w3.w * __shfl(xv, 15, 16);
        atomicAdd(out + ((size_t)pe.y << 4) + o, a);
        pe = pn; xv = xn; j = jn;
    }
}

__global__ __launch_bounds__(256) void relu_kernel(float* __restrict__ out, int n4) {
    int i = blockIdx.x * 256 + threadIdx.x;
    if (i >= n4) return;
    float4* p = (float4*)out + i;
    float4 val = *p;
    val.x = fmaxf(val.x, 0.0f);
    val.y = fmaxf(val.y, 0.0f);
    val.z = fmaxf(val.z, 0.0f);
    val.w = fmaxf(val.w, 0.0f);
    *p = val;
}

// ---------------- Fallback: edge-parallel atomic path ----------------------

__global__ __launch_bounds__(256) void edge_scatter_kernel(
    const float* __restrict__ x, const float* __restrict__ W,
    const int* __restrict__ u, const int* __restrict__ v,
    const int* __restrict__ widx, float* __restrict__ out, int E) {
    int tid = blockIdx.x * 256 + threadIdx.x;
    int e = tid >> 4;
    int o = tid & 15;
    if (e >= E) return;

    int w  = widx[e];
    int uu = u[e];
    int vv = v[e];

    const float* Wr = W + (size_t)w * (D * D) + (size_t)o * D;
    float4 w0 = *(const float4*)(Wr + 0);
    float4 w1 = *(const float4*)(Wr + 4);
    float4 w2 = *(const float4*)(Wr + 8);
    float4 w3 = *(const float4*)(Wr + 12);

    float xv = x[(size_t)uu * D + o];

    float acc = 0.0f;
    acc += w0.x * __shfl(xv,  0, 16);
    acc += w0.y * __shfl(xv,  1, 16);
    acc += w0.z * __shfl(xv,  2, 16);
    acc += w0.w * __shfl(xv,  3, 16);
    acc += w1.x * __shfl(xv,  4, 16);
    acc += w1.y * __shfl(xv,  5, 16);
    acc += w1.z * __shfl(xv,  6, 16);
    acc += w1.w * __shfl(xv,  7, 16);
    acc += w2.x * __shfl(xv,  8, 16);
    acc += w2.y * __shfl(xv,  9, 16);
    acc += w2.z * __shfl(xv, 10, 16);
    acc += w2.w * __shfl(xv, 11, 16);
    acc += w3.x * __shfl(xv, 12, 16);
    acc += w3.y * __shfl(xv, 13, 16);
    acc += w3.z * __shfl(xv, 14, 16);
    acc += w3.w * __shfl(xv, 15, 16);

    atomicAdd(out + (size_t)vv * D + o, acc);
}

extern "C" void kernel_launch(void* const* d_in, const int* in_sizes, int n_in,
                              void* d_out, int out_size, void* d_ws, size_t ws_size,
                              hipStream_t stream) {
    const float* x    = (const float*)d_in[0];
    const float* W    = (const float*)d_in[1];
    const int*   u    = (const int*)d_in[2];
    const int*   v    = (const int*)d_in[3];
    const int*   widx = (const int*)d_in[4];
    float* out = (float*)d_out;

    int E  = in_sizes[2];           // number of edges
    int NW = in_sizes[1] / (D * D); // number of weight matrices
    int B  = (E + CHUNK - 1) / CHUNK;
    int BP = (B + 63) & ~63;        // padded row length for the scan
    int n4 = out_size / 4;

    // Workspace: counts[256][BP] | rowTotal[256] | bucketBase[260] | perm[E] uint2
    size_t counts_b = (size_t)NW_MAX * BP * 4;
    size_t head = counts_b + (size_t)NW_MAX * 4 + 260 * 4;
    size_t need = head + (size_t)E * 8;

    if (NW <= NW_MAX && ws_size >= need) {
        int* counts     = (int*)d_ws;
        int* rowTotal   = (int*)((char*)d_ws + counts_b);
        int* bucketBase = (int*)((char*)d_ws + counts_b + (size_t)NW_MAX * 4);
        uint2* perm     = (uint2*)((char*)d_ws + head);

        hist_kernel<<<B, 256, 0, stream>>>(widx, counts, BP, E, (float4*)out, n4);
        rowscan_kernel<<<64, 256, 0, stream>>>(counts, rowTotal, BP, B);
        basescan_kernel<<<1, 256, 0, stream>>>(rowTotal, bucketBase);
        scatter_kernel<<<B, 256, 0, stream>>>(u, v, widx, counts, bucketBase, perm, BP, E);
        bucket_mm_kernel<<<NW_MAX * NSLICE, 256, 0, stream>>>(x, W, bucketBase, perm, out);
        int rblocks = (n4 + 255) / 256;
        relu_kernel<<<rblocks, 256, 0, stream>>>(out, n4);
    } else {
        // Fallback: original atomic-scatter path.
        hipMemsetAsync(d_out, 0, (size_t)out_size * sizeof(float), stream);
        int total_threads = E * 16;
        int blocks = (total_threads + 255) / 256;
        edge_scatter_kernel<<<blocks, 256, 0, stream>>>(x, W, u, v, widx, out, E);
        int rblocks = (n4 + 255) / 256;
        relu_kernel<<<rblocks, 256, 0, stream>>>(out, n4);
    }
}